// Round 13
// baseline (3472.035 us; speedup 1.0000x reference)
//
#include <hip/hip_runtime.h>
#include <hip/hip_bf16.h>

#define THREADS 256
#define NBLK 512
#define NGRP 32
#define MEMB 16
#define GROWS 64

#define IMGFR 87                 // 64 W2 + 16 W1c + 4 W1a + 2 W3 + 1 vec
#define IMGU (IMGFR*512)         // ushorts per member image
#define ACTOFF ((size_t)MEMB*IMGU*2)     // 1,425,408 B of weight images
#define XSZB   4096              // x: [64][32] bf16
#define H1SZB  65536             // h1: 64 frags (kt16 x rt4)
#define KPSZB  65536             // kpart: [memb16][64][32] bf16
#define ACTB   (XSZB + H1SZB + KPSZB)
#define CNTOFF (ACTOFF + (size_t)NGRP*ACTB)   // 32 groups x 128 B (padded: private line per group)

typedef float f32x4 __attribute__((ext_vector_type(4)));
typedef __bf16 bf16x8 __attribute__((ext_vector_type(8)));
typedef unsigned short u16x4 __attribute__((ext_vector_type(4)));

static __device__ __forceinline__ unsigned short f2bfu(float f) {
    __hip_bfloat16 h = __float2bfloat16(f);
    unsigned short u; __builtin_memcpy(&u, &h, 2); return u;
}
static __device__ __forceinline__ float bfu2f(unsigned short u) {
    unsigned int x = ((unsigned int)u) << 16;
    float f; __builtin_memcpy(&f, &x, 4); return f;
}

#define MFMA(a, b, c) __builtin_amdgcn_mfma_f32_16x16x32_bf16((a), (b), (c), 0, 0, 0)
#define BC(x) __builtin_bit_cast(bf16x8, (x))
#define LOADG(dst, addr) \
    asm volatile("global_load_dwordx4 %0, %1, off" : "=v"(dst) : "v"(addr))
#define SBAR() __builtin_amdgcn_sched_barrier(0)

__global__ void zero_cnt(unsigned* c) { c[blockIdx.x * 256 + threadIdx.x] = 0u; }

// member image frags: fi<64: W2[kt=fi>>2][t=fi&3]; 64..79: W1c[ktc][t]; 80..83: W1a[t];
// 84..85: W3[nt3]; 86: vec (w1t 64 | b1 64 | b2 64 u16, b3 32 f32 @ushort 256).
// frag element: lane l, j -> W[kbase + (l>>4)*8 + j][ncol(l&15)]
__global__ void pack_members(const float* __restrict__ W1, const float* __restrict__ W2,
                             const float* __restrict__ W3, const float* __restrict__ b1,
                             const float* __restrict__ b2, const float* __restrict__ b3,
                             unsigned short* __restrict__ dst) {
    int b = blockIdx.x, m = b / IMGFR, fi = b % IMGFR, lane = threadIdx.x;
    unsigned short* base = dst + (size_t)m * IMGU;
    if (fi == 86) {
        unsigned short* vb = base + 86 * 512;
        for (int i = lane; i < 192; i += 64) {
            int region = i >> 6, o = i & 63, t = o >> 4, zi = o & 15;
            int zcol = (t < 2) ? (m * 32 + t * 16 + zi) : (512 + m * 32 + (t - 2) * 16 + zi);
            float v = (region == 0) ? W1[32 * 1024 + zcol]
                    : (region == 1) ? b1[zcol] : b2[zcol];
            vb[i] = f2bfu(v);
        }
        if (lane < 32) ((float*)(vb + 256))[lane] = b3[lane];
        return;
    }
    const float* W; int kbase, n, N;
    if (fi < 64) {
        int kt = fi >> 2, t = fi & 3;
        int zt = (t < 2) ? (m * 2 + t) : (32 + m * 2 + (t - 2));
        W = W2; N = 1024; kbase = kt * 32; n = zt * 16 + (lane & 15);
    } else if (fi < 80) {
        int fj = fi - 64, ktc = fj >> 2, t = fj & 3;
        int zt = (t < 2) ? (m * 2 + t) : (32 + m * 2 + (t - 2));
        W = W1 + 33 * 1024; N = 1024; kbase = ktc * 32; n = zt * 16 + (lane & 15);
    } else if (fi < 84) {
        int t = fi - 80;
        int zt = (t < 2) ? (m * 2 + t) : (32 + m * 2 + (t - 2));
        W = W1; N = 1024; kbase = 0; n = zt * 16 + (lane & 15);
    } else {
        int nt3 = fi - 84;
        W = W3; N = 32; kbase = m * 32; n = nt3 * 16 + (lane & 15);
    }
    kbase += (lane >> 4) * 8;
    union { unsigned short s[8]; int4 v; } u;
#pragma unroll
    for (int j = 0; j < 8; j++) u.s[j] = f2bfu(W[(size_t)(kbase + j) * N + n]);
    *reinterpret_cast<int4*>(base + (size_t)fi * 512 + lane * 8) = u.v;
}

static __device__ __forceinline__ void group_sync(unsigned* c, unsigned tgt) {
    __syncthreads();
    if (threadIdx.x == 0) {
        __hip_atomic_fetch_add(c, 1u, __ATOMIC_RELEASE, __HIP_MEMORY_SCOPE_AGENT);
        int gd = 0;
        while (__hip_atomic_load(c, __ATOMIC_ACQUIRE, __HIP_MEMORY_SCOPE_AGENT) < tgt) {
            __builtin_amdgcn_s_sleep(2);
            if (++gd > (1 << 22)) break;   // safety valve
        }
    }
    __syncthreads();
}

__global__ __launch_bounds__(THREADS, 2)
void ccnf_main(const float* __restrict__ theta0,
               const float* __restrict__ ctx,
               char* __restrict__ wsb,
               const int* __restrict__ nsteps_p,
               float* __restrict__ out)
{
    // LDS per block: W2 64 KB + h2s 4 KB = 68 KB -> 2 blocks/CU
    __shared__ __align__(16) unsigned short w2s[64 * 512];
    __shared__ __align__(16) unsigned short h2s[4 * 512];

    const int tid = threadIdx.x;
    const int lane = tid & 63, rt = tid >> 6;       // 4 waves = 4 rowtiles
    const int r16 = lane & 15, wq = lane >> 4, rb4 = wq * 4;
    const int b = blockIdx.x, j = b >> 8;
    const int g = ((b & 31) + (j << 3)) & 31;       // co-resident blocks: different groups,
    const int m = ((b >> 5) & 7) | (j << 3);        // same XCD (b%8 == g%8)
    const int row0 = g * GROWS;

    const unsigned short* img = (const unsigned short*)wsb + (size_t)m * IMGU;
    const char* imgb = (const char*)img;
    char* actb = wsb + ACTOFF + (size_t)g * ACTB;
    unsigned short* xgu = (unsigned short*)actb;
    unsigned short* h1u = (unsigned short*)(actb + XSZB);
    unsigned short* kpu = (unsigned short*)(actb + XSZB + H1SZB);
    const char* h1lane = (const char*)h1u + lane * 16;
    unsigned* cnt = (unsigned*)(wsb + CNTOFF) + g * 32;   // 128 B per group: private line

    // ---- prologue A: stage W1c (16 frags) + ctx (16 frags) into w2s (transient) ----
#pragma unroll
    for (int q = 0; q < 4; ++q) {
        int idx = rt * 4 + q;
        __builtin_amdgcn_global_load_lds(
            (const __attribute__((address_space(1))) void*)(imgb + (size_t)(64 + idx) * 1024 + lane * 16),
            (__attribute__((address_space(3))) void*)(w2s + idx * 512), 16, 0, 0);
    }
#pragma unroll
    for (int q = 0; q < 32; ++q) {       // 64 rows x 128 ctx cols -> B-frags at w2s[16..32)
        int e = q * THREADS + tid;
        int r = e >> 7, c = e & 127;
        float v = ctx[(size_t)(row0 + r) * 128 + c];
        w2s[(16 + (c >> 5) * 4 + (r >> 4)) * 512 + (((c & 31) >> 3) * 16 + (r & 15)) * 8 + (c & 7)]
            = f2bfu(v);
    }
    __syncthreads();

    // ---- cxt1 in VGPRs: wave rt computes its 4 z-tiles over its rows ----
    u16x4 cxt[4];
#pragma unroll
    for (int t = 0; t < 4; ++t) {
        f32x4 a = {0.f, 0.f, 0.f, 0.f};
#pragma unroll
        for (int ktc = 0; ktc < 4; ++ktc) {
            bf16x8 wf = *(const bf16x8*)(w2s + (ktc * 4 + t) * 512 + lane * 8);
            bf16x8 cf = *(const bf16x8*)(w2s + (16 + ktc * 4 + rt) * 512 + lane * 8);
            a = MFMA(wf, cf, a);
        }
#pragma unroll
        for (int i = 0; i < 4; ++i) cxt[t][i] = f2bfu(a[i]);
    }
    __syncthreads();   // staging consumed; w2s free for W2

    // ---- prologue B: W2 (64 frags) -> LDS; small weights -> VGPRs; owner inits x ----
#pragma unroll
    for (int q = 0; q < 16; ++q) {
        int idx = rt * 16 + q;
        __builtin_amdgcn_global_load_lds(
            (const __attribute__((address_space(1))) void*)(imgb + (size_t)idx * 1024 + lane * 16),
            (__attribute__((address_space(3))) void*)(w2s + idx * 512), 16, 0, 0);
    }
    bf16x8 w1aF[4], w3F[2];
    u16x4 w1tr[4], b1r[4], b2r[4];
#pragma unroll
    for (int t = 0; t < 4; ++t) {
        w1aF[t] = *(const bf16x8*)(img + (size_t)(80 + t) * 512 + lane * 8);
        const unsigned short* vec = img + 86 * 512;
        w1tr[t] = *(const u16x4*)(vec + t * 16 + rb4);
        b1r[t]  = *(const u16x4*)(vec + 64 + t * 16 + rb4);
        b2r[t]  = *(const u16x4*)(vec + 128 + t * 16 + rb4);
    }
    w3F[0] = *(const bf16x8*)(img + (size_t)84 * 512 + lane * 8);
    w3F[1] = *(const bf16x8*)(img + (size_t)85 * 512 + lane * 8);

    const int orow = m * 4 + (tid >> 3);            // owner row (tid<32)
    const int d0 = (tid & 7) * 4;
    f32x4 th = {0.f, 0.f, 0.f, 0.f}, acck = {0.f, 0.f, 0.f, 0.f};
    float4 b3v = {0.f, 0.f, 0.f, 0.f};
    if (tid < 32) {
        b3v = *(const float4*)((const float*)(img + 86 * 512 + 256) + d0);
        float4 t4 = *(const float4*)(theta0 + (size_t)(row0 + orow) * 32 + d0);
        th[0] = t4.x; th[1] = t4.y; th[2] = t4.z; th[3] = t4.w;
        u16x4 xo;
#pragma unroll
        for (int i = 0; i < 4; ++i) xo[i] = f2bfu(th[i]);
        *(u16x4*)(xgu + orow * 32 + d0) = xo;
    }
    const int nst = nsteps_p[0];
    const float dt = 1.0f / (float)nst;

    unsigned sync_no = 1;
    group_sync(cnt, MEMB * sync_no); sync_no++;     // x0 visible group-wide (also drains W2 DMA)

    const int ne = 4 * nst;
#pragma unroll 1
    for (int e = 0; e < ne; ++e) {
        const int s = e & 3;
        const float tt = (float)(e >> 2) * dt + ((s == 0) ? 0.f : (s == 3) ? dt : 0.5f * dt);

        // === L1: z = x@W1a + cxt1 + b1 + tt*w1t; GLU -> global h1 frag(m*4+rt) ===
        {
            bf16x8 xf = *(const bf16x8*)(xgu + (rt * 16 + r16) * 32 + wq * 8);
            f32x4 z4[4];
#pragma unroll
            for (int t = 0; t < 4; ++t) {
                f32x4 z = {0.f, 0.f, 0.f, 0.f};
                z4[t] = MFMA(w1aF[t], xf, z);
            }
            unsigned short* fb = h1u + (size_t)(m * 4 + rt) * 512;
#pragma unroll
            for (int t = 0; t < 2; ++t) {
                u16x4 o;
#pragma unroll
                for (int i = 0; i < 4; ++i) {
                    float va = z4[t][i] + bfu2f(cxt[t][i]) + bfu2f(b1r[t][i]) + tt * bfu2f(w1tr[t][i]);
                    float vb = z4[t+2][i] + bfu2f(cxt[t+2][i]) + bfu2f(b1r[t+2][i]) + tt * bfu2f(w1tr[t+2][i]);
                    o[i] = f2bfu(va * (1.f / (1.f + __expf(-vb))));
                }
                *(u16x4*)(fb + ((t * 2 + (wq >> 1)) * 16 + r16) * 8 + (wq & 1) * 4) = o;
            }
        }
        group_sync(cnt, MEMB * sync_no); sync_no++;   // h1 ready

        // === L2: 16 h1 frags (global, pipelined) x resident W2 (LDS) ===
        {
            f32x4 acc[4];
#pragma unroll
            for (int t = 0; t < 4; ++t) { f32x4 z = {0.f,0.f,0.f,0.f}; acc[t] = z; }
            f32x4 gb[4];
            LOADG(gb[0], h1lane + (0 * 4 + rt) * 1024);
            LOADG(gb[1], h1lane + (1 * 4 + rt) * 1024);
            LOADG(gb[2], h1lane + (2 * 4 + rt) * 1024);
            LOADG(gb[3], h1lane + (3 * 4 + rt) * 1024);
#pragma unroll
            for (int kt = 0; kt < 16; ++kt) {
                if (kt < 13)       asm volatile("s_waitcnt vmcnt(3)" ::: "memory");
                else if (kt == 13) asm volatile("s_waitcnt vmcnt(2)" ::: "memory");
                else if (kt == 14) asm volatile("s_waitcnt vmcnt(1)" ::: "memory");
                else               asm volatile("s_waitcnt vmcnt(0)" ::: "memory");
                SBAR();
                bf16x8 hf = BC(gb[kt & 3]);
                acc[0] = MFMA(*(const bf16x8*)(w2s + (kt * 4 + 0) * 512 + lane * 8), hf, acc[0]);
                acc[1] = MFMA(*(const bf16x8*)(w2s + (kt * 4 + 1) * 512 + lane * 8), hf, acc[1]);
                acc[2] = MFMA(*(const bf16x8*)(w2s + (kt * 4 + 2) * 512 + lane * 8), hf, acc[2]);
                acc[3] = MFMA(*(const bf16x8*)(w2s + (kt * 4 + 3) * 512 + lane * 8), hf, acc[3]);
                SBAR();
                if (kt < 12) LOADG(gb[kt & 3], h1lane + ((kt + 4) * 4 + rt) * 1024);
            }
            // GLU(+b2) -> h2s frag rt (block-local)
#pragma unroll
            for (int t = 0; t < 2; ++t) {
                u16x4 o;
#pragma unroll
                for (int i = 0; i < 4; ++i) {
                    float va = acc[t][i] + bfu2f(b2r[t][i]);
                    float vb = acc[t+2][i] + bfu2f(b2r[t+2][i]);
                    o[i] = f2bfu(va * (1.f / (1.f + __expf(-vb))));
                }
                *(u16x4*)(h2s + rt * 512 + ((t * 2 + (wq >> 1)) * 16 + r16) * 8 + (wq & 1) * 4) = o;
            }
        }
        __syncthreads();   // h2s ready (same-wave, but keep block-safe)

        // === L3: kpart = h2-slice @ W3-slice -> global kpart[m] (bf16) ===
        {
            bf16x8 h2f = *(const bf16x8*)(h2s + rt * 512 + lane * 8);
#pragma unroll
            for (int n = 0; n < 2; ++n) {
                f32x4 z = {0.f, 0.f, 0.f, 0.f};
                f32x4 a3 = MFMA(w3F[n], h2f, z);
                u16x4 o;
#pragma unroll
                for (int i = 0; i < 4; ++i) o[i] = f2bfu(a3[i]);
                *(u16x4*)(kpu + m * 2048 + (rt * 16 + r16) * 32 + n * 16 + rb4) = o;
            }
        }
        group_sync(cnt, MEMB * sync_no); sync_no++;   // kparts ready

        // === RK4 (distributed): owner reduces its 4 rows, broadcasts x ===
        if (tid < 32) {
            float kv[4] = {b3v.x, b3v.y, b3v.z, b3v.w};
#pragma unroll
            for (int mm = 0; mm < MEMB; ++mm) {
                u16x4 q = *(const u16x4*)(kpu + mm * 2048 + orow * 32 + d0);
#pragma unroll
                for (int i = 0; i < 4; ++i) kv[i] += bfu2f(q[i]);
            }
            u16x4 xo;
#pragma unroll
            for (int i = 0; i < 4; ++i) {
                float xe;
                if (s == 0)      { acck[i] = kv[i];          xe = th[i] + 0.5f * dt * kv[i]; }
                else if (s == 1) { acck[i] += 2.f * kv[i];   xe = th[i] + 0.5f * dt * kv[i]; }
                else if (s == 2) { acck[i] += 2.f * kv[i];   xe = th[i] + dt * kv[i]; }
                else             { th[i] += (dt / 6.f) * (acck[i] + kv[i]); xe = th[i]; }
                xo[i] = f2bfu(xe);
            }
            *(u16x4*)(xgu + orow * 32 + d0) = xo;
        }
        group_sync(cnt, MEMB * sync_no); sync_no++;   // x ready
    }

    if (tid < 32) {
        float4 o; o.x = th[0]; o.y = th[1]; o.z = th[2]; o.w = th[3];
        *(float4*)(out + (size_t)(row0 + orow) * 32 + d0) = o;
    }
}

extern "C" void kernel_launch(void* const* d_in, const int* in_sizes, int n_in,
                              void* d_out, int out_size, void* d_ws, size_t ws_size,
                              hipStream_t stream) {
    const float* theta0 = (const float*)d_in[0];
    const float* ctx    = (const float*)d_in[1];
    const float* W1     = (const float*)d_in[2];
    const float* b1     = (const float*)d_in[3];
    const float* W2     = (const float*)d_in[4];
    const float* b2     = (const float*)d_in[5];
    const float* W3     = (const float*)d_in[6];
    const float* b3     = (const float*)d_in[7];
    const int*   nst    = (const int*)d_in[8];
    float* out = (float*)d_out;
    char*  ws  = (char*)d_ws;

    zero_cnt<<<4, 256, 0, stream>>>((unsigned*)(ws + CNTOFF));
    pack_members<<<MEMB * IMGFR, 64, 0, stream>>>(W1, W2, W3, b1, b2, b3, (unsigned short*)ws);
    ccnf_main<<<NBLK, THREADS, 0, stream>>>(theta0, ctx, ws, nst, out);
}

// Round 14
// 1203.926 us; speedup vs baseline: 2.8839x; 2.8839x over previous
//
#include <hip/hip_runtime.h>
#include <hip/hip_bf16.h>

#define THREADS 512
#define NBLK 256
#define NGRP 32
#define GROWS 64
#define IMGU (173*512)                       // ushorts per member image (173 KB)
#define H1OFF  (8*IMGU*2)                    // 1,417,216 B
#define H1SZ   (NGRP*64*1024)                // 2 MB   (32 groups x 64 frags)
#define KPOFF  (H1OFF + H1SZ)
#define KPSZ   (NGRP*8*4096)                 // 1 MB   (8 members x [64][32] bf16)
#define CNTOFF (KPOFF + KPSZ)                // 32 groups x 256 B (padded: no false sharing)

typedef float f32x4 __attribute__((ext_vector_type(4)));
typedef __bf16 bf16x8 __attribute__((ext_vector_type(8)));
typedef unsigned short u16x4 __attribute__((ext_vector_type(4)));

static __device__ __forceinline__ unsigned short f2bfu(float f) {
    __hip_bfloat16 h = __float2bfloat16(f);
    unsigned short u; __builtin_memcpy(&u, &h, 2); return u;
}
static __device__ __forceinline__ float bfu2f(unsigned short u) {
    unsigned int x = ((unsigned int)u) << 16;
    float f; __builtin_memcpy(&f, &x, 4); return f;
}

#define MFMA(a, b, c) __builtin_amdgcn_mfma_f32_16x16x32_bf16((a), (b), (c), 0, 0, 0)
#define BC(x) __builtin_bit_cast(bf16x8, (x))
#define LOADG(dst, addr) \
    asm volatile("global_load_dwordx4 %0, %1, off" : "=v"(dst) : "v"(addr))
#define SBAR() __builtin_amdgcn_sched_barrier(0)

__global__ void zero_cnt(unsigned* c) { c[blockIdx.x * 256 + threadIdx.x] = 0u; }

// Per-member weight image: 128 W2 frags | 32 W1c frags | 8 W1a frags | 4 W3 frags | vec block.
// Frag element: lane l, j -> W[k = kt*32 + (l>>4)*8 + j][n = ntg*16 + (l&15)]
__global__ void pack_members(const float* __restrict__ W1, const float* __restrict__ W2,
                             const float* __restrict__ W3, const float* __restrict__ b1,
                             const float* __restrict__ b2, const float* __restrict__ b3,
                             unsigned short* __restrict__ dst) {
    int b = blockIdx.x, m = b / 173, fi = b % 173, lane = threadIdx.x;
    unsigned short* base = dst + (size_t)m * IMGU;
    if (fi == 172) {   // vec block: w1tA|w1tB|b1A|b1B|b2A|b2B (64 u16 each) + b3 (32 f32)
        unsigned short* vb = base + 172 * 512;
        for (int i = lane; i < 384; i += 64) {
            int region = i >> 6, o = i & 63;
            int cA = m * 64 + o, cB = 512 + m * 64 + o;
            float v = 0.f;
            if (region == 0) v = W1[32 * 1024 + cA];
            else if (region == 1) v = W1[32 * 1024 + cB];
            else if (region == 2) v = b1[cA];
            else if (region == 3) v = b1[cB];
            else if (region == 4) v = b2[cA];
            else                  v = b2[cB];
            vb[i] = f2bfu(v);
        }
        if (lane < 32) ((float*)(vb + 384))[lane] = b3[lane];
        return;
    }
    const float* W; int kbase, n, N;
    if (fi < 128) {        // W2 slice frags: idx = kt*8 + ntl
        int kt = fi >> 3, ntl = fi & 7;
        int ntg = (ntl < 4) ? (m * 4 + ntl) : (32 + m * 4 + (ntl - 4));
        W = W2; N = 1024; kbase = kt * 32; n = ntg * 16 + (lane & 15);
    } else if (fi < 160) { // W1c frags: idx = ktc*8 + ntl (ctx rows 33..160)
        int fj = fi - 128, ktc = fj >> 3, ntl = fj & 7;
        int ntg = (ntl < 4) ? (m * 4 + ntl) : (32 + m * 4 + (ntl - 4));
        W = W1 + 33 * 1024; N = 1024; kbase = ktc * 32; n = ntg * 16 + (lane & 15);
    } else if (fi < 168) { // W1a frags: idx = ntl (theta rows 0..31)
        int ntl = fi - 160;
        int ntg = (ntl < 4) ? (m * 4 + ntl) : (32 + m * 4 + (ntl - 4));
        W = W1; N = 1024; kbase = 0; n = ntg * 16 + (lane & 15);
    } else {               // W3 frags: idx = ktl*2 + nt3 (K-slice rows m*64..)
        int fj = fi - 168, ktl = fj >> 1, nt3 = fj & 1;
        W = W3; N = 32; kbase = m * 64 + ktl * 32; n = nt3 * 16 + (lane & 15);
    }
    kbase += (lane >> 4) * 8;
    union { unsigned short s[8]; int4 v; } u;
#pragma unroll
    for (int j = 0; j < 8; j++) u.s[j] = f2bfu(W[(size_t)(kbase + j) * N + n]);
    *reinterpret_cast<int4*>(base + (size_t)fi * 512 + lane * 8) = u.v;
}

// Spin with RELAXED loads (atomics hit the coherence point; no per-poll buffer_inv),
// then ONE acquire fence. Release-add unchanged.
static __device__ __forceinline__ void group_sync(unsigned* c, unsigned tgt) {
    __syncthreads();
    if (threadIdx.x == 0) {
        __hip_atomic_fetch_add(c, 1u, __ATOMIC_RELEASE, __HIP_MEMORY_SCOPE_AGENT);
        int gd = 0;
        while (__hip_atomic_load(c, __ATOMIC_RELAXED, __HIP_MEMORY_SCOPE_AGENT) < tgt) {
            __builtin_amdgcn_s_sleep(2);
            if (++gd > (1 << 22)) break;   // safety valve: terminate, never hang
        }
        __builtin_amdgcn_fence(__ATOMIC_ACQUIRE, "agent");   // single invalidation per sync
    }
    __syncthreads();
}

__global__ __launch_bounds__(THREADS, 2)
void ccnf_main(const float* __restrict__ theta0,
               const float* __restrict__ ctx,
               char* __restrict__ wsb,
               const int* __restrict__ nsteps_p,
               float* __restrict__ out)
{
    // LDS: W2 128K | cxt1 16K | h2 8K | x 4K = 156 KB (1 block/CU)
    __shared__ __align__(16) unsigned short w2s[128 * 512];
    __shared__ __align__(16) unsigned short cxts[32 * 64 * 4];  // [z4][row][4] (conflict-free)
    __shared__ __align__(16) unsigned short h2s[8 * 512];       // frag(ktl*4+rt)
    __shared__ __align__(16) unsigned short als[2048];          // x frags [d>>3][row][d&7]

    const int tid = threadIdx.x;
    const int lane = tid & 63, wv = tid >> 6;
    const int rt = wv & 3, nh = wv >> 2;            // wave -> (rowtile, n-half)
    const int r16 = lane & 15, wq = lane >> 4, rb4 = wq * 4;
    const int row = rt * 16 + r16;
    const int g = blockIdx.x & 31, m = blockIdx.x >> 5;
    const int row0 = g * GROWS;

    const unsigned short* img = (const unsigned short*)wsb + (size_t)m * IMGU;
    unsigned short* h1u = (unsigned short*)(wsb + H1OFF) + (size_t)g * (64 * 512);
    unsigned short* kpu = (unsigned short*)(wsb + KPOFF) + (size_t)g * (8 * 2048);
    unsigned* cnt = (unsigned*)(wsb + CNTOFF) + g * 64;   // 256 B per group: private line
    const char* h1lane = (const char*)h1u + lane * 16;

    // ---- resident VGPR constants ----
    bf16x8 w1aA[2], w1aB[2], w3f[2];
    u16x4 w1tA[2], w1tB[2], b1A[2], b1B[2], b2A[2], b2B[2];
#pragma unroll
    for (int k = 0; k < 2; ++k) {
        w1aA[k] = *(const bf16x8*)(img + (160 + 2 * nh + k) * 512 + lane * 8);
        w1aB[k] = *(const bf16x8*)(img + (164 + 2 * nh + k) * 512 + lane * 8);
        w3f[k]  = *(const bf16x8*)(img + (168 + k * 2 + nh) * 512 + lane * 8);
        int cl = (2 * nh + k) * 16 + rb4;
        const unsigned short* vu = img + 172 * 512;
        w1tA[k] = *(const u16x4*)(vu + cl);       w1tB[k] = *(const u16x4*)(vu + 64 + cl);
        b1A[k]  = *(const u16x4*)(vu + 128 + cl); b1B[k]  = *(const u16x4*)(vu + 192 + cl);
        b2A[k]  = *(const u16x4*)(vu + 256 + cl); b2B[k]  = *(const u16x4*)(vu + 320 + cl);
    }
    const int rowc = tid >> 3, db = (tid & 7) * 4;
    const float4 b3v = *(const float4*)((const float*)(img + 172 * 512 + 384) + db);

    // ---- prologue: W1c -> LDS (transient), ctx staging, theta ----
#pragma unroll
    for (int q = 0; q < 4; ++q) {   // 32 W1c frags -> w2s[0..32)
        int idx = wv * 4 + q;
        __builtin_amdgcn_global_load_lds(
            (const __attribute__((address_space(1))) void*)((const char*)img + (size_t)(128 + idx) * 1024 + lane * 16),
            (__attribute__((address_space(3))) void*)(w2s + idx * 512), 16, 0, 0);
    }
    {   // ctx [64 rows][128] fp32 -> staging frags at w2s[32*512..]
        const float* cp = ctx + (size_t)(row0 + rowc) * 128 + (tid & 7) * 16;
        float4 v0 = ((const float4*)cp)[0], v1 = ((const float4*)cp)[1];
        float4 v2 = ((const float4*)cp)[2], v3 = ((const float4*)cp)[3];
        int c0 = (tid & 7) * 16;
        unsigned short* sb = w2s + 16384 + (c0 >> 5) * 2048 + ((c0 & 31) >> 3) * 512 + rowc * 8;
        u16x4 o;
        o[0]=f2bfu(v0.x); o[1]=f2bfu(v0.y); o[2]=f2bfu(v0.z); o[3]=f2bfu(v0.w); *(u16x4*)(sb) = o;
        o[0]=f2bfu(v1.x); o[1]=f2bfu(v1.y); o[2]=f2bfu(v1.z); o[3]=f2bfu(v1.w); *(u16x4*)(sb + 4) = o;
        o[0]=f2bfu(v2.x); o[1]=f2bfu(v2.y); o[2]=f2bfu(v2.z); o[3]=f2bfu(v2.w); *(u16x4*)(sb + 512) = o;
        o[0]=f2bfu(v3.x); o[1]=f2bfu(v3.y); o[2]=f2bfu(v3.z); o[3]=f2bfu(v3.w); *(u16x4*)(sb + 516) = o;
    }
    float th[4], acck[4];
    {
        float4 t0 = *(const float4*)(theta0 + (size_t)(row0 + rowc) * 32 + db);
        th[0]=t0.x; th[1]=t0.y; th[2]=t0.z; th[3]=t0.w;
        acck[0]=acck[1]=acck[2]=acck[3]=0.f;
        u16x4 xo; xo[0]=f2bfu(t0.x); xo[1]=f2bfu(t0.y); xo[2]=f2bfu(t0.z); xo[3]=f2bfu(t0.w);
        *(u16x4*)(als + (db >> 3) * 512 + rowc * 8 + (db & 7)) = xo;
    }
    const int nst = nsteps_p[0];
    const float dt = 1.0f / (float)nst;
    __syncthreads();

    // ---- cxt1 = ctx @ W1c-slice; store z4-major [z4][row][4] ----
#pragma unroll
    for (int ab = 0; ab < 2; ++ab)
#pragma unroll
        for (int k = 0; k < 2; ++k) {
            int ntl = ab * 4 + 2 * nh + k;
            f32x4 a = {0.f, 0.f, 0.f, 0.f};
#pragma unroll
            for (int ktc = 0; ktc < 4; ++ktc) {
                bf16x8 cf = *(const bf16x8*)(w2s + 16384 + ktc * 2048 + wq * 512 + row * 8);
                bf16x8 wf = *(const bf16x8*)(w2s + (ktc * 8 + ntl) * 512 + lane * 8);
                a = MFMA(wf, cf, a);
            }
            u16x4 o;
#pragma unroll
            for (int i = 0; i < 4; ++i) o[i] = f2bfu(a[i]);
            int z4 = ab * 16 + (2 * nh + k) * 4 + wq;
            *(u16x4*)(cxts + (z4 * 64 + row) * 4) = o;
        }
    __syncthreads();   // W1c/ctx staging consumed; w2s free

    // ---- W2 slice -> LDS (resident) ----
#pragma unroll
    for (int q = 0; q < 16; ++q) {
        int idx = wv * 16 + q;
        __builtin_amdgcn_global_load_lds(
            (const __attribute__((address_space(1))) void*)((const char*)img + (size_t)idx * 1024 + lane * 16),
            (__attribute__((address_space(3))) void*)(w2s + idx * 512), 16, 0, 0);
    }
    __syncthreads();

    // ---- main loop: 4*nst evals, 2 group-syncs each ----
    const int ne = 4 * nst;
    for (int e = 0; e < ne; ++e) {
        const int s = e & 3;
        const float tt = (float)(e >> 2) * dt + ((s == 0) ? 0.f : (s == 3) ? dt : 0.5f * dt);

        // === L1: z-slice = x@W1a + cxt1 + b1 + t*w1t; GLU -> global h1 frag(2m+nh, rt) ===
        {
            bf16x8 xf = *(const bf16x8*)(als + wq * 512 + row * 8);
            unsigned short* fb = h1u + ((2 * m + nh) * 4 + rt) * 512;
#pragma unroll
            for (int k = 0; k < 2; ++k) {
                f32x4 z = {0.f, 0.f, 0.f, 0.f};
                f32x4 zA = MFMA(w1aA[k], xf, z);
                f32x4 zB = MFMA(w1aB[k], xf, z);
                int zA4 = (2 * nh + k) * 4 + wq, zB4 = 16 + zA4;
                u16x4 cA = *(const u16x4*)(cxts + (zA4 * 64 + row) * 4);
                u16x4 cB = *(const u16x4*)(cxts + (zB4 * 64 + row) * 4);
                u16x4 o;
#pragma unroll
                for (int i = 0; i < 4; ++i) {
                    float va = zA[i] + bfu2f(cA[i]) + bfu2f(b1A[k][i]) + tt * bfu2f(w1tA[k][i]);
                    float vb = zB[i] + bfu2f(cB[i]) + bfu2f(b1B[k][i]) + tt * bfu2f(w1tB[k][i]);
                    o[i] = f2bfu(va * (1.f / (1.f + __expf(-vb))));
                }
                *(u16x4*)(fb + (k * 2 + (wq >> 1)) * 128 + r16 * 8 + (wq & 1) * 4) = o;
            }
        }
        group_sync(&cnt[0], 8u * (unsigned)(e + 1));   // h1 ready group-wide

        // === L2: stream 16 h1 B-frags (global), A = resident W2 (LDS) ===
        {
            f32x4 acc[4];
#pragma unroll
            for (int p = 0; p < 4; ++p) { f32x4 z = {0.f,0.f,0.f,0.f}; acc[p] = z; }
            f32x4 gb[4];
            LOADG(gb[0], h1lane + (0 * 4 + rt) * 1024);
            LOADG(gb[1], h1lane + (1 * 4 + rt) * 1024);
            LOADG(gb[2], h1lane + (2 * 4 + rt) * 1024);
            LOADG(gb[3], h1lane + (3 * 4 + rt) * 1024);
#pragma unroll
            for (int kt = 0; kt < 16; ++kt) {
                if (kt < 13)      asm volatile("s_waitcnt vmcnt(3)" ::: "memory");
                else if (kt == 13) asm volatile("s_waitcnt vmcnt(2)" ::: "memory");
                else if (kt == 14) asm volatile("s_waitcnt vmcnt(1)" ::: "memory");
                else               asm volatile("s_waitcnt vmcnt(0)" ::: "memory");
                SBAR();
                bf16x8 hf = BC(gb[kt & 3]);
                acc[0] = MFMA(*(const bf16x8*)(w2s + (kt * 8 + 2 * nh + 0) * 512 + lane * 8), hf, acc[0]);
                acc[1] = MFMA(*(const bf16x8*)(w2s + (kt * 8 + 2 * nh + 1) * 512 + lane * 8), hf, acc[1]);
                acc[2] = MFMA(*(const bf16x8*)(w2s + (kt * 8 + 4 + 2 * nh + 0) * 512 + lane * 8), hf, acc[2]);
                acc[3] = MFMA(*(const bf16x8*)(w2s + (kt * 8 + 4 + 2 * nh + 1) * 512 + lane * 8), hf, acc[3]);
                SBAR();
                if (kt < 12) LOADG(gb[kt & 3], h1lane + ((kt + 4) * 4 + rt) * 1024);
            }
            // GLU(+b2) -> h2s frag(nh*4+rt) (LDS, block-local)
#pragma unroll
            for (int k = 0; k < 2; ++k) {
                u16x4 o;
#pragma unroll
                for (int i = 0; i < 4; ++i) {
                    float va = acc[k][i] + bfu2f(b2A[k][i]);
                    float vb = acc[2 + k][i] + bfu2f(b2B[k][i]);
                    o[i] = f2bfu(va * (1.f / (1.f + __expf(-vb))));
                }
                *(u16x4*)(h2s + (nh * 4 + rt) * 512 + (k * 2 + (wq >> 1)) * 128 + r16 * 8 + (wq & 1) * 4) = o;
            }
        }
        __syncthreads();   // h2s ready

        // === L3: k-partial = h2-slice @ W3-slice -> global kpart[m] (bf16) ===
        {
            f32x4 a3 = {0.f, 0.f, 0.f, 0.f};
#pragma unroll
            for (int ktl = 0; ktl < 2; ++ktl) {
                bf16x8 hf = *(const bf16x8*)(h2s + (ktl * 4 + rt) * 512 + lane * 8);
                a3 = MFMA(w3f[ktl], hf, a3);
            }
            u16x4 o;
#pragma unroll
            for (int i = 0; i < 4; ++i) o[i] = f2bfu(a3[i]);
            *(u16x4*)(kpu + m * 2048 + row * 32 + nh * 16 + rb4) = o;
        }
        group_sync(&cnt[1], 8u * (unsigned)(e + 1));   // kparts ready group-wide

        // === RK4 combine (replicated in all members; x stays local) ===
        {
            float kv[4] = {b3v.x, b3v.y, b3v.z, b3v.w};
#pragma unroll
            for (int mm = 0; mm < 8; ++mm) {
                u16x4 q = *(const u16x4*)(kpu + mm * 2048 + rowc * 32 + db);
#pragma unroll
                for (int i = 0; i < 4; ++i) kv[i] += bfu2f(q[i]);
            }
            u16x4 xo;
#pragma unroll
            for (int i = 0; i < 4; ++i) {
                float xe;
                if (s == 0)      { acck[i] = kv[i];          xe = th[i] + 0.5f * dt * kv[i]; }
                else if (s == 1) { acck[i] += 2.f * kv[i];   xe = th[i] + 0.5f * dt * kv[i]; }
                else if (s == 2) { acck[i] += 2.f * kv[i];   xe = th[i] + dt * kv[i]; }
                else             { th[i] += (dt / 6.f) * (acck[i] + kv[i]); xe = th[i]; }
                xo[i] = f2bfu(xe);
            }
            *(u16x4*)(als + (db >> 3) * 512 + rowc * 8 + (db & 7)) = xo;
        }
        __syncthreads();   // x ready for next eval
    }

    if (m == 0) {
        float4 o; o.x = th[0]; o.y = th[1]; o.z = th[2]; o.w = th[3];
        *(float4*)(out + (size_t)(row0 + rowc) * 32 + db) = o;
    }
}

extern "C" void kernel_launch(void* const* d_in, const int* in_sizes, int n_in,
                              void* d_out, int out_size, void* d_ws, size_t ws_size,
                              hipStream_t stream) {
    const float* theta0 = (const float*)d_in[0];
    const float* ctx    = (const float*)d_in[1];
    const float* W1     = (const float*)d_in[2];
    const float* b1     = (const float*)d_in[3];
    const float* W2     = (const float*)d_in[4];
    const float* b2     = (const float*)d_in[5];
    const float* W3     = (const float*)d_in[6];
    const float* b3     = (const float*)d_in[7];
    const int*   nst    = (const int*)d_in[8];
    float* out = (float*)d_out;
    char*  ws  = (char*)d_ws;

    zero_cnt<<<8, 256, 0, stream>>>((unsigned*)(ws + CNTOFF));
    pack_members<<<8 * 173, 64, 0, stream>>>(W1, W2, W3, b1, b2, b3, (unsigned short*)ws);
    ccnf_main<<<NBLK, THREADS, 0, stream>>>(theta0, ctx, ws, nst, out);
}

// Round 15
// 380.266 us; speedup vs baseline: 9.1305x; 3.1660x over previous
//
#include <hip/hip_runtime.h>
#include <hip/hip_bf16.h>

#define THREADS 512
#define NBLK 256
#define NGRP 32
#define GROWS 64
#define IMGU (173*512)                       // ushorts per member image (173 KB)
#define H1OFF  (8*IMGU*2)                    // 1,417,216 B
#define H1SZ   (NGRP*64*1024)                // 2 MB   (32 groups x 64 frags)
#define KPOFF  (H1OFF + H1SZ)
#define KPSZ   (NGRP*8*4096)                 // 1 MB   (8 members x [64][32] bf16)
#define CNTOFF (KPOFF + KPSZ)                // 32 groups x 256 B (padded: no false sharing)

typedef float f32x4 __attribute__((ext_vector_type(4)));
typedef int   i32x2 __attribute__((ext_vector_type(2)));
typedef __bf16 bf16x8 __attribute__((ext_vector_type(8)));
typedef unsigned short u16x4 __attribute__((ext_vector_type(4)));

static __device__ __forceinline__ unsigned short f2bfu(float f) {
    __hip_bfloat16 h = __float2bfloat16(f);
    unsigned short u; __builtin_memcpy(&u, &h, 2); return u;
}
static __device__ __forceinline__ float bfu2f(unsigned short u) {
    unsigned int x = ((unsigned int)u) << 16;
    float f; __builtin_memcpy(&f, &x, 4); return f;
}

#define MFMA(a, b, c) __builtin_amdgcn_mfma_f32_16x16x32_bf16((a), (b), (c), 0, 0, 0)
#define BC(x)  __builtin_bit_cast(bf16x8, (x))
#define BC2(x) __builtin_bit_cast(i32x2, (x))
#define BCU(x) __builtin_bit_cast(u16x4, (x))

// agent-scope (sc1) communication ops: write-through to MALL / read MALL, bypass L1+L2.
#define LOADG(dst, addr) \
    asm volatile("global_load_dwordx4 %0, %1, off sc1" : "=v"(dst) : "v"(addr))
#define LOADC2(dst, addr) \
    asm volatile("global_load_dwordx2 %0, %1, off sc1" : "=v"(dst) : "v"(addr))
#define STOREC8(addr, val) \
    asm volatile("global_store_dwordx2 %0, %1, off sc1" :: "v"(addr), "v"(val) : "memory")
#define SBAR() __builtin_amdgcn_sched_barrier(0)

__global__ void zero_cnt(unsigned* c) { c[blockIdx.x * 256 + threadIdx.x] = 0u; }

// Per-member weight image: 128 W2 frags | 32 W1c frags | 8 W1a frags | 4 W3 frags | vec block.
// Frag element: lane l, j -> W[k = kt*32 + (l>>4)*8 + j][n = ntg*16 + (l&15)]
__global__ void pack_members(const float* __restrict__ W1, const float* __restrict__ W2,
                             const float* __restrict__ W3, const float* __restrict__ b1,
                             const float* __restrict__ b2, const float* __restrict__ b3,
                             unsigned short* __restrict__ dst) {
    int b = blockIdx.x, m = b / 173, fi = b % 173, lane = threadIdx.x;
    unsigned short* base = dst + (size_t)m * IMGU;
    if (fi == 172) {   // vec block: w1tA|w1tB|b1A|b1B|b2A|b2B (64 u16 each) + b3 (32 f32)
        unsigned short* vb = base + 172 * 512;
        for (int i = lane; i < 384; i += 64) {
            int region = i >> 6, o = i & 63;
            int cA = m * 64 + o, cB = 512 + m * 64 + o;
            float v = 0.f;
            if (region == 0) v = W1[32 * 1024 + cA];
            else if (region == 1) v = W1[32 * 1024 + cB];
            else if (region == 2) v = b1[cA];
            else if (region == 3) v = b1[cB];
            else if (region == 4) v = b2[cA];
            else                  v = b2[cB];
            vb[i] = f2bfu(v);
        }
        if (lane < 32) ((float*)(vb + 384))[lane] = b3[lane];
        return;
    }
    const float* W; int kbase, n, N;
    if (fi < 128) {        // W2 slice frags: idx = kt*8 + ntl
        int kt = fi >> 3, ntl = fi & 7;
        int ntg = (ntl < 4) ? (m * 4 + ntl) : (32 + m * 4 + (ntl - 4));
        W = W2; N = 1024; kbase = kt * 32; n = ntg * 16 + (lane & 15);
    } else if (fi < 160) { // W1c frags: idx = ktc*8 + ntl (ctx rows 33..160)
        int fj = fi - 128, ktc = fj >> 3, ntl = fj & 7;
        int ntg = (ntl < 4) ? (m * 4 + ntl) : (32 + m * 4 + (ntl - 4));
        W = W1 + 33 * 1024; N = 1024; kbase = ktc * 32; n = ntg * 16 + (lane & 15);
    } else if (fi < 168) { // W1a frags: idx = ntl (theta rows 0..31)
        int ntl = fi - 160;
        int ntg = (ntl < 4) ? (m * 4 + ntl) : (32 + m * 4 + (ntl - 4));
        W = W1; N = 1024; kbase = 0; n = ntg * 16 + (lane & 15);
    } else {               // W3 frags: idx = ktl*2 + nt3 (K-slice rows m*64..)
        int fj = fi - 168, ktl = fj >> 1, nt3 = fj & 1;
        W = W3; N = 32; kbase = m * 64 + ktl * 32; n = nt3 * 16 + (lane & 15);
    }
    kbase += (lane >> 4) * 8;
    union { unsigned short s[8]; int4 v; } u;
#pragma unroll
    for (int j = 0; j < 8; j++) u.s[j] = f2bfu(W[(size_t)(kbase + j) * N + n]);
    *reinterpret_cast<int4*>(base + (size_t)fi * 512 + lane * 8) = u.v;
}

// No-fence sync: comm data moves via sc1 (MALL-coherent), so no wbl2/inv needed.
// __syncthreads() drains each wave's vmem (sc1 stores visible at MALL) before the add.
static __device__ __forceinline__ void group_sync(unsigned* c, unsigned tgt) {
    __syncthreads();
    if (threadIdx.x == 0) {
        asm volatile("s_waitcnt vmcnt(0)" ::: "memory");
        __hip_atomic_fetch_add(c, 1u, __ATOMIC_RELAXED, __HIP_MEMORY_SCOPE_AGENT);
        int gd = 0;
        while (__hip_atomic_load(c, __ATOMIC_RELAXED, __HIP_MEMORY_SCOPE_AGENT) < tgt) {
            __builtin_amdgcn_s_sleep(2);
            if (++gd > (1 << 22)) break;   // safety valve: terminate, never hang
        }
    }
    __syncthreads();
}

__global__ __launch_bounds__(THREADS, 2)
void ccnf_main(const float* __restrict__ theta0,
               const float* __restrict__ ctx,
               char* __restrict__ wsb,
               const int* __restrict__ nsteps_p,
               float* __restrict__ out)
{
    // LDS: W2 128K | cxt1 16K | h2 8K | x 4K = 156 KB (1 block/CU)
    __shared__ __align__(16) unsigned short w2s[128 * 512];
    __shared__ __align__(16) unsigned short cxts[32 * 64 * 4];  // [z4][row][4] (conflict-free)
    __shared__ __align__(16) unsigned short h2s[8 * 512];       // frag(ktl*4+rt)
    __shared__ __align__(16) unsigned short als[2048];          // x frags [d>>3][row][d&7]

    const int tid = threadIdx.x;
    const int lane = tid & 63, wv = tid >> 6;
    const int rt = wv & 3, nh = wv >> 2;            // wave -> (rowtile, n-half)
    const int r16 = lane & 15, wq = lane >> 4, rb4 = wq * 4;
    const int row = rt * 16 + r16;
    const int g = blockIdx.x & 31, m = blockIdx.x >> 5;
    const int row0 = g * GROWS;

    const unsigned short* img = (const unsigned short*)wsb + (size_t)m * IMGU;
    unsigned short* h1u = (unsigned short*)(wsb + H1OFF) + (size_t)g * (64 * 512);
    unsigned short* kpu = (unsigned short*)(wsb + KPOFF) + (size_t)g * (8 * 2048);
    unsigned* cnt = (unsigned*)(wsb + CNTOFF) + g * 64;   // 256 B per group: private line
    const char* h1lane = (const char*)h1u + lane * 16;

    // ---- resident VGPR constants ----
    bf16x8 w1aA[2], w1aB[2], w3f[2];
    u16x4 w1tA[2], w1tB[2], b1A[2], b1B[2], b2A[2], b2B[2];
#pragma unroll
    for (int k = 0; k < 2; ++k) {
        w1aA[k] = *(const bf16x8*)(img + (160 + 2 * nh + k) * 512 + lane * 8);
        w1aB[k] = *(const bf16x8*)(img + (164 + 2 * nh + k) * 512 + lane * 8);
        w3f[k]  = *(const bf16x8*)(img + (168 + k * 2 + nh) * 512 + lane * 8);
        int cl = (2 * nh + k) * 16 + rb4;
        const unsigned short* vu = img + 172 * 512;
        w1tA[k] = *(const u16x4*)(vu + cl);       w1tB[k] = *(const u16x4*)(vu + 64 + cl);
        b1A[k]  = *(const u16x4*)(vu + 128 + cl); b1B[k]  = *(const u16x4*)(vu + 192 + cl);
        b2A[k]  = *(const u16x4*)(vu + 256 + cl); b2B[k]  = *(const u16x4*)(vu + 320 + cl);
    }
    const int rowc = tid >> 3, db = (tid & 7) * 4;
    const float4 b3v = *(const float4*)((const float*)(img + 172 * 512 + 384) + db);

    // ---- prologue: W1c -> LDS (transient), ctx staging, theta ----
#pragma unroll
    for (int q = 0; q < 4; ++q) {   // 32 W1c frags -> w2s[0..32)
        int idx = wv * 4 + q;
        __builtin_amdgcn_global_load_lds(
            (const __attribute__((address_space(1))) void*)((const char*)img + (size_t)(128 + idx) * 1024 + lane * 16),
            (__attribute__((address_space(3))) void*)(w2s + idx * 512), 16, 0, 0);
    }
    {   // ctx [64 rows][128] fp32 -> staging frags at w2s[32*512..]
        const float* cp = ctx + (size_t)(row0 + rowc) * 128 + (tid & 7) * 16;
        float4 v0 = ((const float4*)cp)[0], v1 = ((const float4*)cp)[1];
        float4 v2 = ((const float4*)cp)[2], v3 = ((const float4*)cp)[3];
        int c0 = (tid & 7) * 16;
        unsigned short* sb = w2s + 16384 + (c0 >> 5) * 2048 + ((c0 & 31) >> 3) * 512 + rowc * 8;
        u16x4 o;
        o[0]=f2bfu(v0.x); o[1]=f2bfu(v0.y); o[2]=f2bfu(v0.z); o[3]=f2bfu(v0.w); *(u16x4*)(sb) = o;
        o[0]=f2bfu(v1.x); o[1]=f2bfu(v1.y); o[2]=f2bfu(v1.z); o[3]=f2bfu(v1.w); *(u16x4*)(sb + 4) = o;
        o[0]=f2bfu(v2.x); o[1]=f2bfu(v2.y); o[2]=f2bfu(v2.z); o[3]=f2bfu(v2.w); *(u16x4*)(sb + 512) = o;
        o[0]=f2bfu(v3.x); o[1]=f2bfu(v3.y); o[2]=f2bfu(v3.z); o[3]=f2bfu(v3.w); *(u16x4*)(sb + 516) = o;
    }
    float th[4], acck[4];
    {
        float4 t0 = *(const float4*)(theta0 + (size_t)(row0 + rowc) * 32 + db);
        th[0]=t0.x; th[1]=t0.y; th[2]=t0.z; th[3]=t0.w;
        acck[0]=acck[1]=acck[2]=acck[3]=0.f;
        u16x4 xo; xo[0]=f2bfu(t0.x); xo[1]=f2bfu(t0.y); xo[2]=f2bfu(t0.z); xo[3]=f2bfu(t0.w);
        *(u16x4*)(als + (db >> 3) * 512 + rowc * 8 + (db & 7)) = xo;
    }
    const int nst = nsteps_p[0];
    const float dt = 1.0f / (float)nst;
    __syncthreads();

    // ---- cxt1 = ctx @ W1c-slice; store z4-major [z4][row][4] ----
#pragma unroll
    for (int ab = 0; ab < 2; ++ab)
#pragma unroll
        for (int k = 0; k < 2; ++k) {
            int ntl = ab * 4 + 2 * nh + k;
            f32x4 a = {0.f, 0.f, 0.f, 0.f};
#pragma unroll
            for (int ktc = 0; ktc < 4; ++ktc) {
                bf16x8 cf = *(const bf16x8*)(w2s + 16384 + ktc * 2048 + wq * 512 + row * 8);
                bf16x8 wf = *(const bf16x8*)(w2s + (ktc * 8 + ntl) * 512 + lane * 8);
                a = MFMA(wf, cf, a);
            }
            u16x4 o;
#pragma unroll
            for (int i = 0; i < 4; ++i) o[i] = f2bfu(a[i]);
            int z4 = ab * 16 + (2 * nh + k) * 4 + wq;
            *(u16x4*)(cxts + (z4 * 64 + row) * 4) = o;
        }
    __syncthreads();   // W1c/ctx staging consumed; w2s free

    // ---- W2 slice -> LDS (resident) ----
#pragma unroll
    for (int q = 0; q < 16; ++q) {
        int idx = wv * 16 + q;
        __builtin_amdgcn_global_load_lds(
            (const __attribute__((address_space(1))) void*)((const char*)img + (size_t)idx * 1024 + lane * 16),
            (__attribute__((address_space(3))) void*)(w2s + idx * 512), 16, 0, 0);
    }
    __syncthreads();

    // ---- main loop: 4*nst evals, 2 group-syncs each ----
    const int ne = 4 * nst;
    for (int e = 0; e < ne; ++e) {
        const int s = e & 3;
        const float tt = (float)(e >> 2) * dt + ((s == 0) ? 0.f : (s == 3) ? dt : 0.5f * dt);

        // === L1: z-slice = x@W1a + cxt1 + b1 + t*w1t; GLU -> global h1 frag(2m+nh, rt) ===
        {
            bf16x8 xf = *(const bf16x8*)(als + wq * 512 + row * 8);
            unsigned short* fb = h1u + ((2 * m + nh) * 4 + rt) * 512;
#pragma unroll
            for (int k = 0; k < 2; ++k) {
                f32x4 z = {0.f, 0.f, 0.f, 0.f};
                f32x4 zA = MFMA(w1aA[k], xf, z);
                f32x4 zB = MFMA(w1aB[k], xf, z);
                int zA4 = (2 * nh + k) * 4 + wq, zB4 = 16 + zA4;
                u16x4 cA = *(const u16x4*)(cxts + (zA4 * 64 + row) * 4);
                u16x4 cB = *(const u16x4*)(cxts + (zB4 * 64 + row) * 4);
                u16x4 o;
#pragma unroll
                for (int i = 0; i < 4; ++i) {
                    float va = zA[i] + bfu2f(cA[i]) + bfu2f(b1A[k][i]) + tt * bfu2f(w1tA[k][i]);
                    float vb = zB[i] + bfu2f(cB[i]) + bfu2f(b1B[k][i]) + tt * bfu2f(w1tB[k][i]);
                    o[i] = f2bfu(va * (1.f / (1.f + __expf(-vb))));
                }
                STOREC8(fb + (k * 2 + (wq >> 1)) * 128 + r16 * 8 + (wq & 1) * 4, BC2(o));
            }
        }
        group_sync(&cnt[0], 8u * (unsigned)(e + 1));   // h1 ready group-wide

        // === L2: stream 16 h1 B-frags (MALL, 8-deep pipeline), A = resident W2 (LDS) ===
        {
            f32x4 acc[4];
#pragma unroll
            for (int p = 0; p < 4; ++p) { f32x4 z = {0.f,0.f,0.f,0.f}; acc[p] = z; }
            f32x4 gb[8];
#pragma unroll
            for (int q = 0; q < 8; ++q) LOADG(gb[q], h1lane + (q * 4 + rt) * 1024);
#pragma unroll
            for (int kt = 0; kt < 16; ++kt) {
                if (kt <= 8)       asm volatile("s_waitcnt vmcnt(7)" ::: "memory");
                else if (kt == 9)  asm volatile("s_waitcnt vmcnt(6)" ::: "memory");
                else if (kt == 10) asm volatile("s_waitcnt vmcnt(5)" ::: "memory");
                else if (kt == 11) asm volatile("s_waitcnt vmcnt(4)" ::: "memory");
                else if (kt == 12) asm volatile("s_waitcnt vmcnt(3)" ::: "memory");
                else if (kt == 13) asm volatile("s_waitcnt vmcnt(2)" ::: "memory");
                else if (kt == 14) asm volatile("s_waitcnt vmcnt(1)" ::: "memory");
                else               asm volatile("s_waitcnt vmcnt(0)" ::: "memory");
                SBAR();
                bf16x8 hf = BC(gb[kt & 7]);
                acc[0] = MFMA(*(const bf16x8*)(w2s + (kt * 8 + 2 * nh + 0) * 512 + lane * 8), hf, acc[0]);
                acc[1] = MFMA(*(const bf16x8*)(w2s + (kt * 8 + 2 * nh + 1) * 512 + lane * 8), hf, acc[1]);
                acc[2] = MFMA(*(const bf16x8*)(w2s + (kt * 8 + 4 + 2 * nh + 0) * 512 + lane * 8), hf, acc[2]);
                acc[3] = MFMA(*(const bf16x8*)(w2s + (kt * 8 + 4 + 2 * nh + 1) * 512 + lane * 8), hf, acc[3]);
                SBAR();
                if (kt < 8) LOADG(gb[kt & 7], h1lane + ((kt + 8) * 4 + rt) * 1024);
            }
            // GLU(+b2) -> h2s frag(nh*4+rt) (LDS, block-local)
#pragma unroll
            for (int k = 0; k < 2; ++k) {
                u16x4 o;
#pragma unroll
                for (int i = 0; i < 4; ++i) {
                    float va = acc[k][i] + bfu2f(b2A[k][i]);
                    float vb = acc[2 + k][i] + bfu2f(b2B[k][i]);
                    o[i] = f2bfu(va * (1.f / (1.f + __expf(-vb))));
                }
                *(u16x4*)(h2s + (nh * 4 + rt) * 512 + (k * 2 + (wq >> 1)) * 128 + r16 * 8 + (wq & 1) * 4) = o;
            }
        }
        __syncthreads();   // h2s ready

        // === L3: k-partial = h2-slice @ W3-slice -> global kpart[m] (bf16, sc1) ===
        {
            f32x4 a3 = {0.f, 0.f, 0.f, 0.f};
#pragma unroll
            for (int ktl = 0; ktl < 2; ++ktl) {
                bf16x8 hf = *(const bf16x8*)(h2s + (ktl * 4 + rt) * 512 + lane * 8);
                a3 = MFMA(w3f[ktl], hf, a3);
            }
            u16x4 o;
#pragma unroll
            for (int i = 0; i < 4; ++i) o[i] = f2bfu(a3[i]);
            STOREC8(kpu + m * 2048 + row * 32 + nh * 16 + rb4, BC2(o));
        }
        group_sync(&cnt[1], 8u * (unsigned)(e + 1));   // kparts ready group-wide

        // === RK4 combine (replicated; kpart read from MALL via sc1) ===
        {
            i32x2 kq[8];
#pragma unroll
            for (int mm = 0; mm < 8; ++mm)
                LOADC2(kq[mm], kpu + mm * 2048 + rowc * 32 + db);
            asm volatile("s_waitcnt vmcnt(0)" ::: "memory");
            SBAR();
            float kv[4] = {b3v.x, b3v.y, b3v.z, b3v.w};
#pragma unroll
            for (int mm = 0; mm < 8; ++mm) {
                u16x4 q = BCU(kq[mm]);
#pragma unroll
                for (int i = 0; i < 4; ++i) kv[i] += bfu2f(q[i]);
            }
            u16x4 xo;
#pragma unroll
            for (int i = 0; i < 4; ++i) {
                float xe;
                if (s == 0)      { acck[i] = kv[i];          xe = th[i] + 0.5f * dt * kv[i]; }
                else if (s == 1) { acck[i] += 2.f * kv[i];   xe = th[i] + 0.5f * dt * kv[i]; }
                else if (s == 2) { acck[i] += 2.f * kv[i];   xe = th[i] + dt * kv[i]; }
                else             { th[i] += (dt / 6.f) * (acck[i] + kv[i]); xe = th[i]; }
                xo[i] = f2bfu(xe);
            }
            *(u16x4*)(als + (db >> 3) * 512 + rowc * 8 + (db & 7)) = xo;
        }
        __syncthreads();   // x ready for next eval
    }

    if (m == 0) {
        float4 o; o.x = th[0]; o.y = th[1]; o.z = th[2]; o.w = th[3];
        *(float4*)(out + (size_t)(row0 + rowc) * 32 + db) = o;
    }
}

extern "C" void kernel_launch(void* const* d_in, const int* in_sizes, int n_in,
                              void* d_out, int out_size, void* d_ws, size_t ws_size,
                              hipStream_t stream) {
    const float* theta0 = (const float*)d_in[0];
    const float* ctx    = (const float*)d_in[1];
    const float* W1     = (const float*)d_in[2];
    const float* b1     = (const float*)d_in[3];
    const float* W2     = (const float*)d_in[4];
    const float* b2     = (const float*)d_in[5];
    const float* W3     = (const float*)d_in[6];
    const float* b3     = (const float*)d_in[7];
    const int*   nst    = (const int*)d_in[8];
    float* out = (float*)d_out;
    char*  ws  = (char*)d_ws;

    zero_cnt<<<8, 256, 0, stream>>>((unsigned*)(ws + CNTOFF));
    pack_members<<<8 * 173, 64, 0, stream>>>(W1, W2, W3, b1, b2, b3, (unsigned short*)ws);
    ccnf_main<<<NBLK, THREADS, 0, stream>>>(theta0, ctx, ws, nst, out);
}